// Round 2
// baseline (80.933 us; speedup 1.0000x reference)
//
#include <hip/hip_runtime.h>
#include <hip/hip_bf16.h>

typedef __attribute__((ext_vector_type(8))) __bf16 bf16x8;
typedef __attribute__((ext_vector_type(4))) float f32x4;

#define B_M 256
#define K_D 512
#define N_C 100000
#define BN 64
#define BKS 64                 /* K per pipeline step */
#define NSTEP (K_D / BKS)      /* 8 */
#define NBLK ((N_C + BN - 1) / BN)   /* 1563 */

__device__ __forceinline__ unsigned short f2bf(float x) {
  unsigned int u = __float_as_uint(x);
  u += 0x7fffu + ((u >> 16) & 1u);          // round-to-nearest-even
  return (unsigned short)(u >> 16);
}

// one barrier per K-step: drain LDS ops only, keep global loads in flight
__device__ __forceinline__ void block_sync() {
  asm volatile("s_waitcnt lgkmcnt(0)" ::: "memory");
  __builtin_amdgcn_s_barrier();
  __builtin_amdgcn_sched_barrier(0);
}

// ---------------- kernel 1: row-normalize emb -> bf16 ff (linear layout) ----------------
__global__ __launch_bounds__(256) void norm_kernel(const float* __restrict__ emb,
                                                   unsigned short* __restrict__ ff) {
  const int row = blockIdx.x;
  const int t = threadIdx.x;
  float a = emb[row * K_D + t];
  float b = emb[row * K_D + t + 256];
  float ss = a * a + b * b;
  #pragma unroll
  for (int o = 32; o > 0; o >>= 1) ss += __shfl_down(ss, o, 64);
  __shared__ float red[4];
  const int wid = t >> 6, lane = t & 63;
  if (lane == 0) red[wid] = ss;
  __syncthreads();
  float tot = red[0] + red[1] + red[2] + red[3];
  float rn = 1.0f / fmaxf(sqrtf(tot), 1e-12f);
  ff[row * K_D + t]       = f2bf(a * rn);
  ff[row * K_D + t + 256] = f2bf(b * rn);
}

// ---------------- kernel 2: fused GEMM + circle-loss partial reduce ----------------
// 8 waves; wave w owns M rows [32w, 32w+32), all 64 N-cols of the block tile.
// A fragments live in registers (prefetched 1 step ahead from L2-resident ff).
// B (W tile) double-buffered in LDS, reg-staged with depth-3 global prefetch.
__global__ __launch_bounds__(512) void gemm_loss_kernel(const unsigned short* __restrict__ ff,
                                                        const float* __restrict__ W,
                                                        const int* __restrict__ labels,
                                                        double* __restrict__ partials) {
  __shared__ __align__(16) unsigned short Bs[2][BN * BKS];  // 2 x 8 KB, XOR-swizzled
  __shared__ int lbl[B_M];
  __shared__ double red[16];

  const int tid = threadIdx.x;
  const int wid = tid >> 6;
  const int lane = tid & 63;
  const int l15 = lane & 15;
  const int lhi = lane >> 4;
  const int n0 = blockIdx.x * BN;

  if (tid < B_M) lbl[tid] = labels[tid];

  // W staging geometry: thread -> (col, 8-float chunk)
  const int bcol = tid >> 3;              // 0..63
  const int bk8  = tid & 7;               // 0..7
  const bool valid = (n0 + bcol) < N_C;
  const float* wp = W + (long long)(n0 + bcol) * K_D + bk8 * 8;
  const int woff = (bcol * 128 + bk8 * 16) ^ ((bcol & 7) << 4);

  // A fragment base: frag(mt,ks,t) at ap + mt*16*K_D + t*BKS + ks*32
  const unsigned short* ap = ff + (wid * 32 + l15) * K_D + lhi * 8;

  f32x4 acc[2][4] = {};
  float4 wf0[3], wf1[3];                  // depth-3 W prefetch (f32, pre-convert)
  bf16x8 acur[2][2], anxt[2][2];

  // ---- prologue ----
  #pragma unroll
  for (int mt = 0; mt < 2; ++mt)
    #pragma unroll
    for (int ks = 0; ks < 2; ++ks)
      acur[mt][ks] = *reinterpret_cast<const bf16x8*>(ap + mt * 16 * K_D + ks * 32);

  #pragma unroll
  for (int s = 0; s < 3; ++s) {
    if (valid) {
      wf0[s] = *reinterpret_cast<const float4*>(wp + s * BKS);
      wf1[s] = *reinterpret_cast<const float4*>(wp + s * BKS + 4);
    } else {
      wf0[s] = float4{0.f, 0.f, 0.f, 0.f};
      wf1[s] = float4{0.f, 0.f, 0.f, 0.f};
    }
  }
  {
    union { unsigned short us[8]; uint4 v; } pk;
    pk.us[0] = f2bf(wf0[0].x); pk.us[1] = f2bf(wf0[0].y); pk.us[2] = f2bf(wf0[0].z); pk.us[3] = f2bf(wf0[0].w);
    pk.us[4] = f2bf(wf1[0].x); pk.us[5] = f2bf(wf1[0].y); pk.us[6] = f2bf(wf1[0].z); pk.us[7] = f2bf(wf1[0].w);
    *reinterpret_cast<uint4*>(reinterpret_cast<char*>(&Bs[0][0]) + woff) = pk.v;
  }
  block_sync();

  // ---- main pipeline: 8 steps, one barrier each, vmcnt never drained ----
  #pragma unroll
  for (int t = 0; t < NSTEP; ++t) {
    const int cb = t & 1;
    if (t + 3 < NSTEP && valid) {         // issue W(t+3) into set t%3
      wf0[t % 3] = *reinterpret_cast<const float4*>(wp + (t + 3) * BKS);
      wf1[t % 3] = *reinterpret_cast<const float4*>(wp + (t + 3) * BKS + 4);
    }
    if (t + 1 < NSTEP) {
      // A prefetch for next step (L2-resident ff)
      #pragma unroll
      for (int mt = 0; mt < 2; ++mt)
        #pragma unroll
        for (int ks = 0; ks < 2; ++ks)
          anxt[mt][ks] = *reinterpret_cast<const bf16x8*>(ap + mt * 16 * K_D + (t + 1) * BKS + ks * 32);
      // stage B(t+1) into the other buffer (compiler emits counted vmcnt wait)
      const int s = (t + 1) % 3;
      union { unsigned short us[8]; uint4 v; } pk;
      pk.us[0] = f2bf(wf0[s].x); pk.us[1] = f2bf(wf0[s].y); pk.us[2] = f2bf(wf0[s].z); pk.us[3] = f2bf(wf0[s].w);
      pk.us[4] = f2bf(wf1[s].x); pk.us[5] = f2bf(wf1[s].y); pk.us[6] = f2bf(wf1[s].z); pk.us[7] = f2bf(wf1[s].w);
      *reinterpret_cast<uint4*>(reinterpret_cast<char*>(&Bs[cb ^ 1][0]) + woff) = pk.v;
    }
    // compute on Bs[cb]
    #pragma unroll
    for (int fn = 0; fn < 4; ++fn) {
      #pragma unroll
      for (int ks = 0; ks < 2; ++ks) {
        const int col = fn * 16 + l15;
        const int boff = (col * 128 + ks * 64 + lhi * 16) ^ ((col & 7) << 4);
        bf16x8 b = *reinterpret_cast<const bf16x8*>(reinterpret_cast<const char*>(&Bs[cb][0]) + boff);
        #pragma unroll
        for (int mt = 0; mt < 2; ++mt)
          acc[mt][fn] = __builtin_amdgcn_mfma_f32_16x16x32_bf16(acur[mt][ks], b, acc[mt][fn], 0, 0, 0);
      }
    }
    block_sync();
    #pragma unroll
    for (int mt = 0; mt < 2; ++mt)
      #pragma unroll
      for (int ks = 0; ks < 2; ++ks)
        acur[mt][ks] = anxt[mt][ks];
  }

  // ---- fused epilogue: circle-loss terms ----
  float sn_local = 0.0f;
  double sp_local = 0.0;
  #pragma unroll
  for (int mt = 0; mt < 2; ++mt)
    #pragma unroll
    for (int fn = 0; fn < 4; ++fn)
      #pragma unroll
      for (int r = 0; r < 4; ++r) {
        int row = wid * 32 + mt * 16 + lhi * 4 + r;   // C/D: col=lane&15, row=(lane>>4)*4+reg
        int j = n0 + fn * 16 + l15;
        float v = acc[mt][fn][r];
        if (j < N_C) {
          if (j == lbl[row]) {
            double alpha = fmax(1.25 - (double)v, 0.0);     // clamp(Op - sp, 0)
            sp_local += exp(-64.0 * alpha * ((double)v - 0.75));
          } else {
            float an = fmaxf(v + 0.25f, 0.0f);              // clamp(sn + m, 0)
            sn_local += __expf(64.0f * an * (v - 0.25f));
          }
        }
      }

  double sn_d = (double)sn_local;
  #pragma unroll
  for (int o = 32; o > 0; o >>= 1) {
    sn_d     += __shfl_down(sn_d, o, 64);
    sp_local += __shfl_down(sp_local, o, 64);
  }
  if (lane == 0) { red[wid] = sn_d; red[8 + wid] = sp_local; }
  __syncthreads();
  if (tid == 0) {
    double a = 0.0, b = 0.0;
    #pragma unroll
    for (int i = 0; i < 8; ++i) { a += red[i]; b += red[8 + i]; }
    partials[blockIdx.x] = a;          // sn partial
    partials[NBLK + blockIdx.x] = b;   // sp partial
  }
}

// ---------------- kernel 3: final reduce + log1p ----------------
__global__ __launch_bounds__(512) void finalize_kernel(const double* __restrict__ partials,
                                                       float* __restrict__ out) {
  const int t = threadIdx.x;
  double sn = 0.0, sp = 0.0;
  for (int i = t; i < NBLK; i += 512) { sn += partials[i]; sp += partials[NBLK + i]; }
  #pragma unroll
  for (int o = 32; o > 0; o >>= 1) { sn += __shfl_down(sn, o, 64); sp += __shfl_down(sp, o, 64); }
  __shared__ double red[16];
  const int wid = t >> 6, lane = t & 63;
  if (lane == 0) { red[wid] = sn; red[8 + wid] = sp; }
  __syncthreads();
  if (t == 0) {
    double a = 0.0, b = 0.0;
    for (int i = 0; i < 8; ++i) { a += red[i]; b += red[8 + i]; }
    out[0] = (float)log1p(a * b);
  }
}

extern "C" void kernel_launch(void* const* d_in, const int* in_sizes, int n_in,
                              void* d_out, int out_size, void* d_ws, size_t ws_size,
                              hipStream_t stream) {
  // inputs: 0=x (unused), 1=labels (int), 2=emb (f32), 3=W (f32)
  const int*   labels = (const int*)d_in[1];
  const float* emb    = (const float*)d_in[2];
  const float* W      = (const float*)d_in[3];
  float* out = (float*)d_out;

  unsigned short* ff = (unsigned short*)d_ws;                              // 256*512*2 = 262144 B
  double* partials = (double*)((char*)d_ws + (size_t)B_M * K_D * 2);       // 2*1563*8 B

  norm_kernel<<<B_M, 256, 0, stream>>>(emb, ff);
  gemm_loss_kernel<<<NBLK, 512, 0, stream>>>(ff, W, labels, partials);
  finalize_kernel<<<1, 512, 0, stream>>>(partials, out);
}